// Round 4
// baseline (122.990 us; speedup 1.0000x reference)
//
#include <hip/hip_runtime.h>

#define Bx 64
#define Cx 3
#define HIx 224
#define WIx 224
#define HWx (HIx*WIx)      // 50176
#define Hx 32
#define Wx 64
#define URx 10
#define UTx 10
#define HGx (URx*Hx)       // 320
#define WGx (Wx*UTx)       // 640

typedef unsigned int uint4a8 __attribute__((ext_vector_type(4), aligned(8)));

__device__ __forceinline__ unsigned f2bf(float f) {
    unsigned u = __float_as_uint(f);
    return ((u + 0x7fffu + ((u >> 16) & 1u)) >> 16);
}
__device__ __forceinline__ float bf_lo(unsigned u) { return __uint_as_float(u << 16); }
__device__ __forceinline__ float bf_hi(unsigned u) { return __uint_as_float(u & 0xffff0000u); }

// ---------- CHW fp32 -> HWC4 bf16 (8 B/pixel), 2 pixels/thread ----------
__global__ __launch_bounds__(256)
void to_hwc4_bf16(const float2* __restrict__ x2, uint4* __restrict__ xt4) {
    int tid = blockIdx.x * blockDim.x + threadIdx.x;   // over B*HW/2 = 1605632
    const int hw2 = HWx / 2;                            // 25088
    int b = tid / hw2;
    int p = tid - b * hw2;
    const float2* xb = x2 + (size_t)b * Cx * hw2 + p;
    float2 c0 = xb[0];
    float2 c1 = xb[hw2];
    float2 c2 = xb[2 * hw2];
    uint4 o;
    o.x = f2bf(c0.x) | (f2bf(c1.x) << 16);
    o.y = f2bf(c2.x);
    o.z = f2bf(c0.y) | (f2bf(c1.y) << 16);
    o.w = f2bf(c2.y);
    xt4[tid] = o;
}

// ---------- sampler: 4 lanes/pixel, each lane owns a 5x5 quadrant ----------
__global__ __launch_bounds__(256, 4)
void sample_bf16(const uint2* __restrict__ xt,
                 const float* __restrict__ lt,
                 const float2* __restrict__ grid,
                 float* __restrict__ out) {
    // XCD swizzle: 8 images per XCD round, 32 blocks per image
    int bx = blockIdx.x;                 // [0, 2048)
    int xcd = bx & 7;
    int sub = (bx >> 3) & 7;
    int i   = bx >> 6;                   // [0, 32) block-within-image
    int b   = xcd * 8 + sub;             // [0, 64)

    int lane4 = threadIdx.x & 3;
    int pix = i * 64 + (threadIdx.x >> 2);  // [0, 2048) pixel within image
    int oh = pix >> 6;
    int ow = pix & 63;

    float lx = lt[2 * b];
    float ly = lt[2 * b + 1];
    float cxc = fmaf(lx, (WIx * 0.5f), (WIx - 1) * 0.5f);
    float cyc = fmaf(ly, (HIx * 0.5f), (HIx - 1) * 0.5f);

    const uint2* xb = xt + (size_t)b * HWx;
    // lane quadrant: bit1 -> radius half, bit0 -> angle half; 5x5 const offsets
    const float2* gp = grid
        + (size_t)(oh * URx + 5 * (lane4 >> 1)) * WGx
        + ow * UTx + 5 * (lane4 & 1);

    float a0 = 0.f, a1 = 0.f, a2 = 0.f;
#pragma unroll
    for (int ti = 0; ti < 5; ++ti) {
#pragma unroll
        for (int tj = 0; tj < 5; ++tj) {
            float2 g = gp[ti * WGx + tj];            // const offset per step
            float ix = fmaf(g.x, (WIx * 0.5f), cxc); // interior by input ranges
            float iy = fmaf(g.y, (HIx * 0.5f), cyc);
            int x0 = (int)ix;
            int y0 = (int)iy;
            float fx = ix - (float)x0;
            float fy = iy - (float)y0;

            const uint2* p = xb + y0 * WIx + x0;
            uint4a8 r0 = *(const uint4a8*)p;          // (y0,x0),(y0,x0+1)
            uint4a8 r1 = *(const uint4a8*)(p + WIx);  // (y1,x0),(y1,x0+1)

            float m00 = fmaf(fx, bf_lo(r0.z) - bf_lo(r0.x), bf_lo(r0.x));
            float m01 = fmaf(fx, bf_hi(r0.z) - bf_hi(r0.x), bf_hi(r0.x));
            float m02 = fmaf(fx, bf_lo(r0.w) - bf_lo(r0.y), bf_lo(r0.y));
            float m10 = fmaf(fx, bf_lo(r1.z) - bf_lo(r1.x), bf_lo(r1.x));
            float m11 = fmaf(fx, bf_hi(r1.z) - bf_hi(r1.x), bf_hi(r1.x));
            float m12 = fmaf(fx, bf_lo(r1.w) - bf_lo(r1.y), bf_lo(r1.y));
            a0 += fmaf(fy, m10 - m00, m00);
            a1 += fmaf(fy, m11 - m01, m01);
            a2 += fmaf(fy, m12 - m02, m02);
        }
    }

    a0 += __shfl_xor(a0, 1); a0 += __shfl_xor(a0, 2);
    a1 += __shfl_xor(a1, 1); a1 += __shfl_xor(a1, 2);
    a2 += __shfl_xor(a2, 1); a2 += __shfl_xor(a2, 2);

    if (lane4 == 0) {
        const float sc = 1.0f / (URx * UTx);
        int obase = b * (Cx * Hx * Wx) + oh * Wx + ow;
        out[obase]               = a0 * sc;
        out[obase + Hx * Wx]     = a1 * sc;
        out[obase + 2 * Hx * Wx] = a2 * sc;
    }
}

extern "C" void kernel_launch(void* const* d_in, const int* in_sizes, int n_in,
                              void* d_out, int out_size, void* d_ws, size_t ws_size,
                              hipStream_t stream) {
    const float*  x    = (const float*)d_in[0];
    const float*  lt   = (const float*)d_in[1];
    const float2* grid = (const float2*)d_in[2];
    float* out = (float*)d_out;

    uint2* xt = (uint2*)d_ws;                        // 64*50176*8 B = 25.7 MB
    const int total2 = Bx * HWx / 2;                 // 1605632
    to_hwc4_bf16<<<total2 / 256, 256, 0, stream>>>((const float2*)x, (uint4*)d_ws);

    const int n_threads = 4 * Bx * Hx * Wx;          // 524288
    sample_bf16<<<n_threads / 256, 256, 0, stream>>>(xt, lt, grid, out);
}

// Round 5
// 109.905 us; speedup vs baseline: 1.1191x; 1.1191x over previous
//
#include <hip/hip_runtime.h>

#define Bx 64
#define Cx 3
#define HIx 224
#define WIx 224
#define HWx (HIx*WIx)      // 50176
#define Hx 32
#define Wx 64
#define URx 10
#define UTx 10
#define HGx (URx*Hx)       // 320
#define WGx (Wx*UTx)       // 640

typedef unsigned int uint4a8 __attribute__((ext_vector_type(4), aligned(8)));

__device__ __forceinline__ unsigned f2bf(float f) {
    unsigned u = __float_as_uint(f);
    return ((u + 0x7fffu + ((u >> 16) & 1u)) >> 16);
}
__device__ __forceinline__ float bf_lo(unsigned u) { return __uint_as_float(u << 16); }
__device__ __forceinline__ float bf_hi(unsigned u) { return __uint_as_float(u & 0xffff0000u); }

// ---------- CHW fp32 -> HWC4 bf16 (8 B/pixel), 2 pixels/thread ----------
__global__ __launch_bounds__(256)
void to_hwc4_bf16(const float2* __restrict__ x2, uint4* __restrict__ xt4) {
    int tid = blockIdx.x * blockDim.x + threadIdx.x;   // over B*HW/2 = 1605632
    const int hw2 = HWx / 2;                            // 25088
    int b = tid / hw2;
    int p = tid - b * hw2;
    const float2* xb = x2 + (size_t)b * Cx * hw2 + p;
    float2 c0 = xb[0];
    float2 c1 = xb[hw2];
    float2 c2 = xb[2 * hw2];
    uint4 o;
    o.x = f2bf(c0.x) | (f2bf(c1.x) << 16);
    o.y = f2bf(c2.x);
    o.z = f2bf(c0.y) | (f2bf(c1.y) << 16);
    o.w = f2bf(c2.y);
    xt4[tid] = o;
}

// ---- sampler: 4 lanes/pixel, strided (adjacent-angle) samples,
//      5-sample register-staged batches for memory-level parallelism ----
__global__ __launch_bounds__(256)
void sample_bf16(const uint2* __restrict__ xt,
                 const float* __restrict__ lt,
                 const float2* __restrict__ grid,
                 float* __restrict__ out) {
    // XCD swizzle: 8 images per XCD round, 32 blocks per image
    int bx = blockIdx.x;                 // [0, 2048)
    int xcd = bx & 7;
    int sub = (bx >> 3) & 7;
    int i   = bx >> 6;                   // [0, 32) block-within-image
    int b   = xcd * 8 + sub;             // [0, 64)

    int lane4 = threadIdx.x & 3;
    int pix = i * 64 + (threadIdx.x >> 2);  // [0, 2048) pixel within image
    int oh = pix >> 6;
    int ow = pix & 63;

    float lx = lt[2 * b];
    float ly = lt[2 * b + 1];
    float cxc = fmaf(lx, (WIx * 0.5f), (WIx - 1) * 0.5f);
    float cyc = fmaf(ly, (HIx * 0.5f), (HIx - 1) * 0.5f);

    const uint2* xb = xt + (size_t)b * HWx;
    int gbase = (oh * URx) * WGx + ow * UTx;

    float a0 = 0.f, a1 = 0.f, a2 = 0.f;

#pragma unroll
    for (int grp = 0; grp < 5; ++grp) {
        uint4a8 r0[5], r1[5];
        float fx[5], fy[5];
#pragma unroll
        for (int u = 0; u < 5; ++u) {
            int s = 4 * (5 * grp + u) + lane4;   // adjacent lanes -> adjacent angles
            int gi = s / 10;
            int gj = s - 10 * gi;
            float2 g = grid[gbase + gi * WGx + gj];
            float ix = fmaf(g.x, (WIx * 0.5f), cxc);  // interior by input ranges
            float iy = fmaf(g.y, (HIx * 0.5f), cyc);
            int x0 = (int)ix;
            int y0 = (int)iy;
            fx[u] = ix - (float)x0;
            fy[u] = iy - (float)y0;
            const uint2* p = xb + y0 * WIx + x0;
            r0[u] = *(const uint4a8*)p;           // (y0,x0),(y0,x0+1)
            r1[u] = *(const uint4a8*)(p + WIx);   // (y1,x0),(y1,x0+1)
        }
#pragma unroll
        for (int u = 0; u < 5; ++u) {
            float m00 = fmaf(fx[u], bf_lo(r0[u].z) - bf_lo(r0[u].x), bf_lo(r0[u].x));
            float m01 = fmaf(fx[u], bf_hi(r0[u].z) - bf_hi(r0[u].x), bf_hi(r0[u].x));
            float m02 = fmaf(fx[u], bf_lo(r0[u].w) - bf_lo(r0[u].y), bf_lo(r0[u].y));
            float m10 = fmaf(fx[u], bf_lo(r1[u].z) - bf_lo(r1[u].x), bf_lo(r1[u].x));
            float m11 = fmaf(fx[u], bf_hi(r1[u].z) - bf_hi(r1[u].x), bf_hi(r1[u].x));
            float m12 = fmaf(fx[u], bf_lo(r1[u].w) - bf_lo(r1[u].y), bf_lo(r1[u].y));
            a0 += fmaf(fy[u], m10 - m00, m00);
            a1 += fmaf(fy[u], m11 - m01, m01);
            a2 += fmaf(fy[u], m12 - m02, m02);
        }
    }

    a0 += __shfl_xor(a0, 1); a0 += __shfl_xor(a0, 2);
    a1 += __shfl_xor(a1, 1); a1 += __shfl_xor(a1, 2);
    a2 += __shfl_xor(a2, 1); a2 += __shfl_xor(a2, 2);

    if (lane4 == 0) {
        const float sc = 1.0f / (URx * UTx);
        int obase = b * (Cx * Hx * Wx) + oh * Wx + ow;
        out[obase]               = a0 * sc;
        out[obase + Hx * Wx]     = a1 * sc;
        out[obase + 2 * Hx * Wx] = a2 * sc;
    }
}

extern "C" void kernel_launch(void* const* d_in, const int* in_sizes, int n_in,
                              void* d_out, int out_size, void* d_ws, size_t ws_size,
                              hipStream_t stream) {
    const float*  x    = (const float*)d_in[0];
    const float*  lt   = (const float*)d_in[1];
    const float2* grid = (const float2*)d_in[2];
    float* out = (float*)d_out;

    uint2* xt = (uint2*)d_ws;                        // 64*50176*8 B = 25.7 MB
    const int total2 = Bx * HWx / 2;                 // 1605632
    to_hwc4_bf16<<<total2 / 256, 256, 0, stream>>>((const float2*)x, (uint4*)d_ws);

    const int n_threads = 4 * Bx * Hx * Wx;          // 524288
    sample_bf16<<<n_threads / 256, 256, 0, stream>>>(xt, lt, grid, out);
}